// Round 1
// 407.404 us; speedup vs baseline: 1.2908x; 1.2908x over previous
//
#include <hip/hip_runtime.h>

#define TT 512

typedef __attribute__((ext_vector_type(8))) short bf16x8;
typedef __attribute__((ext_vector_type(4))) short s16x4;
typedef __attribute__((ext_vector_type(4))) float f32x4;

__device__ inline short f2bf(float f) {
    // round-to-nearest-even fp32 -> bf16 (values bounded; no NaN path needed)
    unsigned u = __float_as_uint(f);
    u += 0x7FFFu + ((u >> 16) & 1u);
    return (short)(u >> 16);
}

__device__ inline float sigm(float x)  { return __fdividef(1.0f, 1.0f + __expf(-x)); }
__device__ inline float tanh_(float x) { return 1.0f - __fdividef(2.0f, 1.0f + __expf(2.0f * x)); }

#define MFMA16(a, b, c) __builtin_amdgcn_mfma_f32_16x16x32_bf16((a), (b), (c), 0, 0, 0)

// 768 threads = 12 waves = 3 layers x 4 unit-quarters (16 units each).
// WG owns 4 batch rows for all T; grid = 256 = 1 WG/CU.
// Key trick: A-frag rows are REPLICATED (A row r = batch row r>>2), so
// C[r][c] = pre[r>>2][c] and every lane's C reg 0 is exactly its own
// (batchrow=q, unit=n_) preactivation -> no LDS scatter/gather, no shuffles.
// Biases are seeded via the MFMA C operand (loop-invariant frags).
// All of x is staged to LDS up front -> zero global traffic in the loop.
__global__ __launch_bounds__(768, 1)
void gru_fused(const float* __restrict__ x,
               const float* __restrict__ Wih0, const float* __restrict__ Whh0,
               const float* __restrict__ bih0, const float* __restrict__ bhh0,
               const float* __restrict__ Wih1, const float* __restrict__ Whh1,
               const float* __restrict__ bih1, const float* __restrict__ bhh1,
               const float* __restrict__ Wih2, const float* __restrict__ Whh2,
               const float* __restrict__ bih2, const float* __restrict__ bhh2,
               const float* __restrict__ fc1w, const float* __restrict__ fc1b,
               const float* __restrict__ fc2w, const float* __restrict__ fc2b,
               float* __restrict__ out)
{
    // x as bf16: [t][row][32]; k 16..31 kept zero so layer-0 A-frags need no
    // exec masking (q=2,3 read real zeros). Row stride 16 words -> 2-way banks.
    __shared__ __align__(16) short xls[TT][4][32];            // 128 KiB
    // h double buffers: row stride 80 shorts (40 words): A-reads uniform 2-way
    // (free), b16 h-write exactly 1 word/bank (conflict-free). Pads never read.
    __shared__ __align__(16) short hbuf[3][2][4 * 80];        // 3.75 KiB
    __shared__ float h2out[4][64];
    __shared__ float fcz[4][32];

    const int tid = threadIdx.x;
    const int l   = tid & 63;
    const int wid = tid >> 6;                       // 0..11
    const int Ls  = __builtin_amdgcn_readfirstlane(wid >> 2);  // layer 0..2 (scalar)
    const int qt  = wid & 3;                        // unit quarter
    const int n_  = l & 15;                         // A/C col | B col
    const int q   = l >> 4;                         // quad
    const int ar  = n_ >> 2;                        // replicated A row -> batch row
    const int rbase = blockIdx.x * 4;
    const int grow = q;                             // this lane's batch row
    const int u    = qt * 16 + n_;                  // this lane's h unit 0..63

    // ---- LDS init: hbuf = 0 (h(-1)=0), xls upper halves = 0 ----
    for (int i = tid; i < 3 * 2 * 320; i += 768) (&hbuf[0][0][0])[i] = 0;
    {
        const f32x4 z4 = {0.f, 0.f, 0.f, 0.f};
        for (int i = tid; i < 4096; i += 768) {
            const int t = i >> 3, sub = i & 7;
            *(f32x4*)&xls[t][sub >> 1][16 + (sub & 1) * 8] = z4;
        }
    }

    // ---- stage all x for this WG's 4 rows (float4 loads, 4 in flight) ----
    {
        const float4* xv = (const float4*)(x + (size_t)rbase * (TT * 16));
        auto stash = [&](int i, float4 v) {
            const int row = i >> 11, rem = i & 2047;    // 2048 float4 per row
            s16x4 pv = { f2bf(v.x), f2bf(v.y), f2bf(v.z), f2bf(v.w) };
            *(s16x4*)&xls[rem >> 2][row][(rem & 3) * 4] = pv;
        };
        for (int base = tid; base < 8192; base += 3072) {
            const int i1 = base + 768, i2 = base + 1536, i3 = base + 2304;
            float4 v0 = xv[base], v1, v2, v3;
            if (i1 < 8192) v1 = xv[i1];
            if (i2 < 8192) v2 = xv[i2];
            if (i3 < 8192) v3 = xv[i3];
            stash(base, v0);
            if (i1 < 8192) stash(i1, v1);
            if (i2 < 8192) stash(i2, v2);
            if (i3 < 8192) stash(i3, v3);
        }
    }

    // ---- per-wave weight selection ----
    const float* Wih = (Ls == 0) ? Wih0 : (Ls == 1) ? Wih1 : Wih2;
    const float* Whh = (Ls == 0) ? Whh0 : (Ls == 1) ? Whh1 : Whh2;
    const float* bih = (Ls == 0) ? bih0 : (Ls == 1) ? bih1 : bih2;
    const float* bhh = (Ls == 0) ? bhh0 : (Ls == 1) ? bhh1 : bhh2;
    const int ldih = (Ls == 0) ? 16 : 64;   // W_ih0 is [192,16]; K zero-padded

    // ---- resident B-frags: gate g in {0=r,1=z,2=n}, cols g*64+qt*16.. ----
    // B-frag lane layout: col = n_, k = kt*32 + q*8 + j
    bf16x8 wihf[3][2], whhf[3][2];
#pragma unroll
    for (int g = 0; g < 3; ++g) {
        const int gc = g * 64 + qt * 16;
#pragma unroll
        for (int kt = 0; kt < 2; ++kt) {
            const int kb = kt * 32 + q * 8;
            bf16x8 fi, fh;
#pragma unroll
            for (int j = 0; j < 8; ++j) {
                const int k = kb + j;
                float vi = (k < ldih) ? Wih[(gc + n_) * ldih + k] : 0.0f;
                float vh = Whh[(gc + n_) * 64 + k];
                fi[j] = f2bf(vi);
                fh[j] = f2bf(vh);
            }
            wihf[g][kt] = fi;
            whhf[g][kt] = fh;
        }
    }

    // ---- loop-invariant bias fragments (seed MFMA C operand) ----
    const float br  = bih[u] + bhh[u];
    const float bz  = bih[64 + u] + bhh[64 + u];
    const float bxn = bih[128 + u];
    const float bhn = bhh[128 + u];
    const f32x4 fbr  = {br,  br,  br,  br};
    const f32x4 fbz  = {bz,  bz,  bz,  bz};
    const f32x4 fbxn = {bxn, bxn, bxn, bxn};
    const f32x4 fbhn = {bhn, bhn, bhn, bhn};

    float hp = 0.0f;   // this lane's h(row=grow, unit=u), carried fp32
    __syncthreads();

    // ---- pipelined time loop: wave of layer L processes t = s - L ----
    // Unrolled x2 so buffer parity (and thus all LDS addresses) is
    // loop-invariant per copy: bi = tw&1 = (s&1) ^ (L&1) = par ^ (L&1).
#define GRU_STEP(sv, par)                                                        \
    {                                                                            \
        const int tw = (sv) - Ls;                                                \
        if (tw >= 0 && tw < TT) {                                                \
            const int bi = (par) ^ (Ls & 1);                                     \
            const short* own = &hbuf[Ls][bi ^ 1][0];                             \
            const bf16x8 hA0 = *(const bf16x8*)(own + ar * 80 + q * 8);          \
            const bf16x8 hA1 = *(const bf16x8*)(own + ar * 80 + 32 + q * 8);     \
            f32x4 cr, cz, cxn;                                                   \
            if (Ls == 0) {                                                       \
                const bf16x8 iA0 = *(const bf16x8*)(&xls[tw][0][0] + ar * 32 + q * 8); \
                cr  = MFMA16(iA0, wihf[0][0], fbr);                              \
                cz  = MFMA16(iA0, wihf[1][0], fbz);                              \
                cxn = MFMA16(iA0, wihf[2][0], fbxn);                             \
            } else {                                                             \
                const short* inp = &hbuf[Ls - 1][bi][0];                         \
                const bf16x8 iA0 = *(const bf16x8*)(inp + ar * 80 + q * 8);      \
                const bf16x8 iA1 = *(const bf16x8*)(inp + ar * 80 + 32 + q * 8); \
                cr  = MFMA16(iA0, wihf[0][0], fbr);                              \
                cr  = MFMA16(iA1, wihf[0][1], cr);                               \
                cz  = MFMA16(iA0, wihf[1][0], fbz);                              \
                cz  = MFMA16(iA1, wihf[1][1], cz);                               \
                cxn = MFMA16(iA0, wihf[2][0], fbxn);                             \
                cxn = MFMA16(iA1, wihf[2][1], cxn);                              \
            }                                                                    \
            cr  = MFMA16(hA0, whhf[0][0], cr);                                   \
            cr  = MFMA16(hA1, whhf[0][1], cr);                                   \
            cz  = MFMA16(hA0, whhf[1][0], cz);                                   \
            cz  = MFMA16(hA1, whhf[1][1], cz);                                   \
            f32x4 chn = MFMA16(hA0, whhf[2][0], fbhn);                           \
            chn = MFMA16(hA1, whhf[2][1], chn);                                  \
            const float rr = sigm(cr[0]);                                        \
            const float zz = sigm(cz[0]);                                        \
            const float nn = tanh_(cxn[0] + rr * chn[0]);                        \
            const float hv = nn + zz * (hp - nn);                                \
            hp = hv;                                                             \
            hbuf[Ls][bi][grow * 80 + u] = f2bf(hv);                              \
        }                                                                        \
        __syncthreads();                                                         \
    }

    for (int s0 = 0; s0 < TT + 2; s0 += 2) {
        GRU_STEP(s0, 0)
        GRU_STEP(s0 + 1, 1)
    }
#undef GRU_STEP

    // ---- FC head: layer-2 waves hold h2(T-1), one value per lane ----
    if (wid >= 8) h2out[grow][u] = hp;
    __syncthreads();
    if (tid < 128) {
        const int row = tid >> 5, uu = tid & 31;
        float acc = fc1b[uu];
#pragma unroll
        for (int k = 0; k < 64; ++k) acc += h2out[row][k] * fc1w[uu * 64 + k];
        fcz[row][uu] = fmaxf(acc, 0.0f);
    }
    __syncthreads();
    if (tid < 4) {
        float y = fc2b[0];
#pragma unroll
        for (int uu = 0; uu < 32; ++uu) y += fcz[tid][uu] * fc2w[uu];
        out[rbase + tid] = y;
    }
}

extern "C" void kernel_launch(void* const* d_in, const int* in_sizes, int n_in,
                              void* d_out, int out_size, void* d_ws, size_t ws_size,
                              hipStream_t stream) {
    (void)in_sizes; (void)n_in; (void)d_ws; (void)ws_size; (void)out_size;
    gru_fused<<<dim3(256), dim3(768), 0, stream>>>(
        (const float*)d_in[0],
        (const float*)d_in[1],  (const float*)d_in[2],  (const float*)d_in[3],  (const float*)d_in[4],
        (const float*)d_in[5],  (const float*)d_in[6],  (const float*)d_in[7],  (const float*)d_in[8],
        (const float*)d_in[9],  (const float*)d_in[10], (const float*)d_in[11], (const float*)d_in[12],
        (const float*)d_in[13], (const float*)d_in[14], (const float*)d_in[15], (const float*)d_in[16],
        (float*)d_out);
}